// Round 3
// baseline (502.718 us; speedup 1.0000x reference)
//
#include <hip/hip_runtime.h>
#include <hip/hip_bf16.h>

typedef unsigned short u16;
typedef unsigned int u32;

typedef short bf16v8 __attribute__((ext_vector_type(8)));
typedef float f32v4 __attribute__((ext_vector_type(4)));

// ---------------- problem constants ----------------
constexpr int BB   = 64;
constexpr int TT   = 196;
constexpr int NTOK = BB * TT;   // 12544
constexpr int DD   = 512;
constexpr int FF   = 2048;
constexpr int EE   = 8;
constexpr int NBR  = 2;
constexpr int GE   = NBR * EE;  // 16 global experts
constexpr int QS0  = 416;       // queue grid height, MODE0 (balanced ~416 entries/xcd)
constexpr int QS1  = 104;       // MODE1

// meta: [0..15] u-row base per global expert, [16..31] tile count per expert
__device__ __forceinline__ u16 f2bf(float f) {
    union { float f; u32 u; } v; v.f = f;
    u32 r = v.u + 0x7fffu + ((v.u >> 16) & 1u);
    return (u16)(r >> 16);
}

__device__ __forceinline__ float wave_sum(float v) {
    #pragma unroll
    for (int m = 32; m > 0; m >>= 1) v += __shfl_xor(v, m, 64);
    return v;
}

__device__ __forceinline__ float gelu_tanh(float v) {
    float z = 0.7978845608028654f * (v + 0.044715f * v * v * v);
    float az = fabsf(z);
    float e = __expf(-2.0f * az);
    float t = (1.0f - e) / (1.0f + e);
    t = (z < 0.0f) ? -t : t;
    return 0.5f * v * (1.0f + t);
}

__device__ __forceinline__ float silu(float v) {
    return v / (1.0f + __expf(-v));
}

__device__ __forceinline__ void gload16(const u16* g, u16* l) {
    typedef const __attribute__((address_space(1))) unsigned gv_t;
    typedef __attribute__((address_space(3))) unsigned lv_t;
    __builtin_amdgcn_global_load_lds((gv_t*)g, (lv_t*)l, 16, 0, 0);
}

__device__ __forceinline__ void bar() {
    asm volatile("" ::: "memory");
    __builtin_amdgcn_s_barrier();
    asm volatile("" ::: "memory");
}

#define ASM_VMCNT4 asm volatile("s_waitcnt vmcnt(4)" ::: "memory")
#define ASM_VMCNT0 asm volatile("s_waitcnt vmcnt(0)" ::: "memory")
#define ASM_LGKM0  asm volatile("s_waitcnt lgkmcnt(0)" ::: "memory")

// ---------------- transpose f32[R][C] -> bf16[C][R], batched ----------------
__global__ __launch_bounds__(256) void transpose_f32_bf16(
    const float* __restrict__ src, u16* __restrict__ dst, int R, int C)
{
    __shared__ float tile[32][33];
    size_t base = (size_t)blockIdx.z * R * C;
    src += base; dst += base;
    int tx = threadIdx.x, ty = threadIdx.y;
    int c0 = blockIdx.x * 32, r0 = blockIdx.y * 32;
    #pragma unroll
    for (int j = 0; j < 4; ++j)
        tile[ty + 8 * j][tx] = src[(size_t)(r0 + ty + 8 * j) * C + c0 + tx];
    __syncthreads();
    #pragma unroll
    for (int j = 0; j < 4; ++j)
        dst[(size_t)(c0 + ty + 8 * j) * R + r0 + tx] = f2bf(tile[tx][ty + 8 * j]);
}

// ---------------- LN + gate softmax/argmax (wave per token) ----------------
__global__ __launch_bounds__(256) void ln_gate_kernel(
    const float* __restrict__ x, const float* __restrict__ ln_g, const float* __restrict__ ln_b,
    const float* __restrict__ gate_w, const float* __restrict__ gate_b,
    u16* __restrict__ hA, u16* __restrict__ hB,
    int* __restrict__ idxb, float* __restrict__ pbuf)
{
    int wave = threadIdx.x >> 6, lane = threadIdx.x & 63;
    int tok = blockIdx.x * 4 + wave;
    const float* xr = x + (size_t)tok * DD + lane * 8;
    float4 v0 = *(const float4*)xr;
    float4 v1 = *(const float4*)(xr + 4);
    float xs[8] = {v0.x, v0.y, v0.z, v0.w, v1.x, v1.y, v1.z, v1.w};
    float s = 0.f, ss = 0.f;
    #pragma unroll
    for (int i = 0; i < 8; ++i) { s += xs[i]; ss += xs[i] * xs[i]; }
    s = wave_sum(s); ss = wave_sum(ss);
    float mu = s * (1.0f / DD);
    float var = ss * (1.0f / DD) - mu * mu;
    float rstd = rsqrtf(var + 1e-5f);

    #pragma unroll
    for (int br = 0; br < NBR; ++br) {
        u16* hb = br ? hB : hA;
        float part[8] = {0, 0, 0, 0, 0, 0, 0, 0};
        u16 hu[8];
        #pragma unroll
        for (int i = 0; i < 8; ++i) {
            int d = lane * 8 + i;
            float g = ln_g[br * DD + d], b = ln_b[br * DD + d];
            float h = (xs[i] - mu) * rstd * g + b;
            hu[i] = f2bf(h);
            const float* gw = gate_w + ((size_t)br * DD + d) * EE;
            float4 g0 = *(const float4*)gw;
            float4 g1 = *(const float4*)(gw + 4);
            part[0] += h * g0.x; part[1] += h * g0.y; part[2] += h * g0.z; part[3] += h * g0.w;
            part[4] += h * g1.x; part[5] += h * g1.y; part[6] += h * g1.z; part[7] += h * g1.w;
        }
        uint4 pk;
        pk.x = (u32)hu[0] | ((u32)hu[1] << 16);
        pk.y = (u32)hu[2] | ((u32)hu[3] << 16);
        pk.z = (u32)hu[4] | ((u32)hu[5] << 16);
        pk.w = (u32)hu[6] | ((u32)hu[7] << 16);
        *(uint4*)(hb + (size_t)tok * DD + lane * 8) = pk;

        float logit[8];
        #pragma unroll
        for (int e = 0; e < 8; ++e)
            logit[e] = wave_sum(part[e]) + gate_b[br * EE + e];
        float m = logit[0]; int bi = 0;
        #pragma unroll
        for (int e = 1; e < 8; ++e)
            if (logit[e] > m) { m = logit[e]; bi = e; }
        float sum = 0.f;
        #pragma unroll
        for (int e = 0; e < 8; ++e) sum += __expf(logit[e] - m);
        if (lane == 0) {
            idxb[br * NTOK + tok] = bi;
            pbuf[br * NTOK + tok] = 1.0f / sum;
        }
    }
}

// ---------------- routing ----------------
__global__ void route_kernel(const int* __restrict__ idxb, int* __restrict__ cnt,
                             int* __restrict__ list)
{
    int t = blockIdx.x * 256 + threadIdx.x;
    if (t >= NTOK) return;
    #pragma unroll
    for (int br = 0; br < NBR; ++br) {
        int e = idxb[br * NTOK + t];
        int slot = atomicAdd(&cnt[br * EE + e], 1);
        list[((size_t)(br * EE + e)) * NTOK + slot] = t;
    }
}

__global__ void tilestart_kernel(const int* __restrict__ cnt, int* __restrict__ meta)
{
    if (threadIdx.x != 0 || blockIdx.x != 0) return;
    int pp = 0;
    for (int ge = 0; ge < GE; ++ge) {
        meta[ge] = pp;               // u-row base (branch1 continues at NTOK)
        pp += cnt[ge];
        meta[16 + ge] = (cnt[ge] + 127) >> 7;   // tiles
    }
}

// ---------------- grouped MFMA GEMM, 128x128 tile, BK=32, dbuf+counted vmcnt -
// MODE 0: u[pos] = gelu(h[tok] @ W1[ge] + b1[ge])      A gathered via list
// MODE 1: moe{2}[tok] (+)= p * (u[pos] @ W2[ge] + b2)  A dense (routed order)
// MODE 2: dout = xres + A @ owt + out_b                A dense
// MODE 0/1 grid: (8, QS) -> xcd-grouped expert queues; MODE 2 grid: (4, 98)
template<int MODE>
__global__ __launch_bounds__(256, 4) void gemm_tile(
    const u16* __restrict__ A0, const u16* __restrict__ A1,
    const u16* __restrict__ Bt,
    const int* __restrict__ meta, const int* __restrict__ cnt,
    const int* __restrict__ list, const float* __restrict__ pbuf,
    const float* __restrict__ bias,
    u16* __restrict__ uout, float* __restrict__ moeout,
    const float* __restrict__ xres, float* __restrict__ dout,
    int brsel, int addmode, int pboff)
{
    constexpr int K = (MODE == 1) ? FF : DD;
    constexpr int N = (MODE == 0) ? FF : DD;
    constexpr int NT = N / 128;
    constexpr int NSTEP = K / 32;

    __shared__ __align__(16) u16 As[2][128 * 32];
    __shared__ __align__(16) u16 Bs[2][128 * 32];
    __shared__ int rowtok[128];

    int tid = threadIdx.x, wave = tid >> 6, lane = tid & 63;
    int wm = wave >> 1, wn = wave & 1;
    int fr = lane & 15, fc = (lane >> 4) * 8;
    int r0 = wave * 16 + (lane >> 2);
    int hi = lane & 3;

    // ---- queue bounds ----
    int eA = 0, eB = -1, nA = 0, qlen = 1;
    if constexpr (MODE != 2) {
        int q = blockIdx.x;
        if (brsel < 0)       { eA = q;     eB = q + 8; }
        else if (brsel == 0) { eA = q;     eB = -1; }
        else                 { eA = q + 8; eB = -1; }
        nA = meta[16 + eA] * NT;
        qlen = nA + ((eB >= 0) ? meta[16 + eB] * NT : 0);
    }

    for (int j = (MODE == 2) ? 0 : blockIdx.y;
         j < qlen;
         j += (MODE == 2) ? 1 : gridDim.y)
    {
        // ---- decode entry ----
        int ge = 0, rb, ntile, cnt_e = NTOK, pb = 0;
        if constexpr (MODE == 2) {
            rb = blockIdx.y * 128; ntile = blockIdx.x;
        } else {
            int loc;
            if (j < nA) { ge = eA; loc = j; }
            else        { ge = eB; loc = j - nA; }
            ntile = loc % NT;
            rb = (loc / NT) * 128;
            cnt_e = cnt[ge];
            pb = meta[ge] - ((ge >= 8) ? pboff : 0);
        }

        bar();   // LDS reuse fence across queue entries

        // ---- per-entry staging addresses ----
        const u16* Abase;
        if constexpr (MODE == 0) Abase = (ge >= 8) ? A1 : A0;
        else                     Abase = A0;
        const u16* Bte = Bt + ((MODE == 2) ? (size_t)0 : (size_t)ge * FF * DD);

        const u16 *aSrc0, *aSrc1, *bSrc0, *bSrc1;
        if constexpr (MODE == 0) {
            int lb = ge * NTOK;
            int g0 = rb + r0, g1 = g0 + 64;
            int t0 = (g0 < cnt_e) ? list[lb + g0] : list[lb];
            int t1 = (g1 < cnt_e) ? list[lb + g1] : list[lb];
            aSrc0 = Abase + (size_t)t0 * K + hi * 8;
            aSrc1 = Abase + (size_t)t1 * K + hi * 8;
        } else {
            size_t base = (MODE == 1) ? (size_t)(pb + rb) : (size_t)rb;
            aSrc0 = Abase + (base + r0) * (size_t)K + hi * 8;
            aSrc1 = Abase + (base + r0 + 64) * (size_t)K + hi * 8;
        }
        {
            int nrow = ntile * 128 + r0;
            bSrc0 = Bte + (size_t)nrow * K + hi * 8;
            bSrc1 = Bte + (size_t)(nrow + 64) * K + hi * 8;
        }

        if constexpr (MODE == 1) {
            if (tid < 128) {
                int g = rb + tid;
                rowtok[tid] = (g < cnt_e) ? list[ge * NTOK + g] : -1;
            }
            ASM_LGKM0;   // rowtok write complete before this wave's next barrier
        }

        f32v4 acc[4][4];
        #pragma unroll
        for (int mi = 0; mi < 4; ++mi)
            #pragma unroll
            for (int ni = 0; ni < 4; ++ni)
                acc[mi][ni] = (f32v4){0.f, 0.f, 0.f, 0.f};

        // ---- software-pipelined K loop ----
        {
            // stage step 0 into buf 0
            gload16(aSrc0, &As[0][wave * 512]);
            gload16(aSrc1, &As[0][2048 + wave * 512]);
            gload16(bSrc0, &Bs[0][wave * 512]);
            gload16(bSrc1, &Bs[0][2048 + wave * 512]);
        }
        #pragma unroll 2
        for (int t = 0; t < NSTEP; ++t) {
            int cur = t & 1;
            if (t + 1 < NSTEP) {
                int k = (t + 1) * 32;
                gload16(aSrc0 + k, &As[cur ^ 1][wave * 512]);
                gload16(aSrc1 + k, &As[cur ^ 1][2048 + wave * 512]);
                gload16(bSrc0 + k, &Bs[cur ^ 1][wave * 512]);
                gload16(bSrc1 + k, &Bs[cur ^ 1][2048 + wave * 512]);
                ASM_VMCNT4;           // current step's 4 loads done; next 4 in flight
            } else {
                ASM_VMCNT0;
            }
            bar();

            bf16v8 af[4], bfr[4];
            #pragma unroll
            for (int mi = 0; mi < 4; ++mi)
                af[mi] = *(const bf16v8*)&As[cur][(wm * 64 + mi * 16 + fr) * 32 + fc];
            #pragma unroll
            for (int ni = 0; ni < 4; ++ni)
                bfr[ni] = *(const bf16v8*)&Bs[cur][(wn * 64 + ni * 16 + fr) * 32 + fc];
            #pragma unroll
            for (int mi = 0; mi < 4; ++mi)
                #pragma unroll
                for (int ni = 0; ni < 4; ++ni)
                    acc[mi][ni] = __builtin_amdgcn_mfma_f32_16x16x32_bf16(
                        af[mi], bfr[ni], acc[mi][ni], 0, 0, 0);
            bar();
        }

        // ---- epilogue (C/D frag: col = lane&15, row = (lane>>4)*4 + reg) ----
        #pragma unroll
        for (int mi = 0; mi < 4; ++mi) {
            #pragma unroll
            for (int ni = 0; ni < 4; ++ni) {
                int col = ntile * 128 + wn * 64 + ni * 16 + fr;
                float bn = (MODE == 2) ? bias[col] : bias[(size_t)ge * N + col];
                #pragma unroll
                for (int r = 0; r < 4; ++r) {
                    int rr = wm * 64 + mi * 16 + (lane >> 4) * 4 + r;
                    float v = acc[mi][ni][r] + bn;
                    if constexpr (MODE == 0) {
                        if (rb + rr < cnt_e)
                            uout[(size_t)(pb + rb + rr) * FF + col] = f2bf(gelu_tanh(v));
                    } else if constexpr (MODE == 1) {
                        int tok = rowtok[rr];
                        if (tok >= 0) {
                            float val = v * pbuf[(ge >> 3) * NTOK + tok];
                            if (addmode == 2) {
                                moeout[((size_t)(ge >> 3) * NTOK + tok) * DD + col] = val;
                            } else {
                                float* o = &moeout[(size_t)tok * DD + col];
                                if (addmode) *o += val; else *o = val;
                            }
                        }
                    } else {
                        size_t o = (size_t)(rb + rr) * DD + col;
                        dout[o] = xres[o] + v;
                    }
                }
            }
        }
    }
}

// ---------------- eo = silu(emb) @ emb_w + emb_b  [64, 1024] ----------------
__global__ __launch_bounds__(256) void eo_kernel(
    const float* __restrict__ emb, const float* __restrict__ emb_w,
    const float* __restrict__ emb_b, float* __restrict__ eo)
{
    __shared__ float se[4][DD];
    int tid = threadIdx.x;
    int b0 = blockIdx.y * 4;
    int c0 = blockIdx.x * 256 + tid;
    for (int i = tid; i < 4 * DD; i += 256) {
        int b = i >> 9, d = i & (DD - 1);
        se[b][d] = silu(emb[(size_t)(b0 + b) * DD + d]);
    }
    __syncthreads();
    float acc[4] = {0, 0, 0, 0};
    for (int k = 0; k < DD; ++k) {
        float wv = emb_w[(size_t)k * 1024 + c0];
        #pragma unroll
        for (int b = 0; b < 4; ++b) acc[b] += se[b][k] * wv;
    }
    float bb = emb_b[c0];
    #pragma unroll
    for (int b = 0; b < 4; ++b)
        eo[(size_t)(b0 + b) * 1024 + c0] = acc[b] + bb;
}

// ---------------- stylize: LN(moe/NB)*(1+scale)+shift -> silu -> bf16 -------
__global__ __launch_bounds__(256) void stylize_kernel(
    const float* __restrict__ moe, const float* __restrict__ eo,
    const float* __restrict__ sn_g, const float* __restrict__ sn_b,
    u16* __restrict__ sbuf, int two)
{
    int wave = threadIdx.x >> 6, lane = threadIdx.x & 63;
    int tok = blockIdx.x * 4 + wave;
    int b = tok / TT;
    const float* mr = moe + (size_t)tok * DD + lane * 8;
    float4 v0 = *(const float4*)mr;
    float4 v1 = *(const float4*)(mr + 4);
    float os[8] = {v0.x, v0.y, v0.z, v0.w, v1.x, v1.y, v1.z, v1.w};
    if (two) {
        const float* mr2 = mr + (size_t)NTOK * DD;
        float4 w0 = *(const float4*)mr2;
        float4 w1 = *(const float4*)(mr2 + 4);
        os[0] += w0.x; os[1] += w0.y; os[2] += w0.z; os[3] += w0.w;
        os[4] += w1.x; os[5] += w1.y; os[6] += w1.z; os[7] += w1.w;
    }
    #pragma unroll
    for (int i = 0; i < 8; ++i) os[i] *= (1.0f / NBR);
    float s = 0.f, ss = 0.f;
    #pragma unroll
    for (int i = 0; i < 8; ++i) { s += os[i]; ss += os[i] * os[i]; }
    s = wave_sum(s); ss = wave_sum(ss);
    float mu = s * (1.0f / DD);
    float var = ss * (1.0f / DD) - mu * mu;
    float rstd = rsqrtf(var + 1e-5f);
    u16 hu[8];
    #pragma unroll
    for (int i = 0; i < 8; ++i) {
        int d = lane * 8 + i;
        float h = (os[i] - mu) * rstd * sn_g[d] + sn_b[d];
        float sc = eo[(size_t)b * 1024 + d];
        float sh = eo[(size_t)b * 1024 + DD + d];
        h = h * (1.0f + sc) + sh;
        hu[i] = f2bf(silu(h));
    }
    uint4 pk;
    pk.x = (u32)hu[0] | ((u32)hu[1] << 16);
    pk.y = (u32)hu[2] | ((u32)hu[3] << 16);
    pk.z = (u32)hu[4] | ((u32)hu[5] << 16);
    pk.w = (u32)hu[6] | ((u32)hu[7] << 16);
    *(uint4*)(sbuf + (size_t)tok * DD + lane * 8) = pk;
}

// ---------------- host ----------------
extern "C" void kernel_launch(void* const* d_in, const int* in_sizes, int n_in,
                              void* d_out, int out_size, void* d_ws, size_t ws_size,
                              hipStream_t stream)
{
    const float* x      = (const float*)d_in[0];
    const float* emb    = (const float*)d_in[1];
    const float* ln_g   = (const float*)d_in[2];
    const float* ln_b   = (const float*)d_in[3];
    const float* gate_w = (const float*)d_in[4];
    const float* gate_b = (const float*)d_in[5];
    const float* w1     = (const float*)d_in[6];
    const float* b1     = (const float*)d_in[7];
    const float* w2     = (const float*)d_in[8];
    const float* b2     = (const float*)d_in[9];
    const float* emb_w  = (const float*)d_in[10];
    const float* emb_b  = (const float*)d_in[11];
    const float* sn_g   = (const float*)d_in[12];
    const float* sn_b   = (const float*)d_in[13];
    const float* out_w  = (const float*)d_in[14];
    const float* out_b  = (const float*)d_in[15];
    (void)n_in; (void)in_sizes; (void)out_size;

    const size_t szW   = (size_t)GE * FF * DD * 2;
    const size_t szOwt = (size_t)DD * DD * 2;
    const size_t szH   = (size_t)NTOK * DD * 2;
    const size_t szEo  = (size_t)BB * 2 * DD * 4;
    const size_t szP   = (size_t)NBR * NTOK * 4;
    const size_t szCnt = 256, szMeta = 4096;
    const size_t szList = (size_t)GE * NTOK * 4;
    const size_t szU1  = ((size_t)NTOK + 128) * FF * 2;
    const size_t szU2  = ((size_t)2 * NTOK + 128) * FF * 2;
    const size_t szM1  = (size_t)NTOK * DD * 4;
    const size_t szM2  = (size_t)2 * NTOK * DD * 4;

    auto align256 = [](size_t v) { return (v + 255) & ~(size_t)255; };
    size_t fixed = align256(szW) + align256(szW) + align256(szOwt) + align256(szH) * 2 +
                   align256(szEo) + align256(szP) * 2 + align256(szCnt) + align256(szMeta) +
                   align256(szList);
    bool combined = ws_size >= fixed + align256(szU2) + align256(szM2) + (1u << 20);

    char* w = (char*)d_ws;
    size_t off = 0;
    auto take = [&](size_t bytes) -> void* {
        void* p = w + off;
        off = align256(off + bytes);
        return p;
    };
    u16*   w1t  = (u16*)take(szW);
    u16*   w2t  = (u16*)take(szW);
    u16*   owt  = (u16*)take(szOwt);
    u16*   hA   = (u16*)take(szH);       // reused as sbuf
    u16*   hB   = (u16*)take(szH);
    float* eo   = (float*)take(szEo);
    float* pbuf = (float*)take(szP);
    int*   idxb = (int*)take(szP);
    int*   cnt  = (int*)take(szCnt);
    int*   meta = (int*)take(szMeta);
    int*   list = (int*)take(szList);
    u16*   ubuf = (u16*)take(combined ? szU2 : szU1);
    float* moe  = (float*)take(combined ? szM2 : szM1);

    // 1. weight transposes -> bf16 [N][K]
    transpose_f32_bf16<<<dim3(FF / 32, DD / 32, GE), dim3(32, 8), 0, stream>>>(w1, w1t, DD, FF);
    transpose_f32_bf16<<<dim3(DD / 32, FF / 32, GE), dim3(32, 8), 0, stream>>>(w2, w2t, FF, DD);
    transpose_f32_bf16<<<dim3(DD / 32, DD / 32, 1), dim3(32, 8), 0, stream>>>(out_w, owt, DD, DD);

    // 2. LN + gate
    ln_gate_kernel<<<NTOK / 4, 256, 0, stream>>>(x, ln_g, ln_b, gate_w, gate_b, hA, hB, idxb, pbuf);

    // 3. routing
    hipMemsetAsync(cnt, 0, 64, stream);
    route_kernel<<<(NTOK + 255) / 256, 256, 0, stream>>>(idxb, cnt, list);
    tilestart_kernel<<<1, 64, 0, stream>>>(cnt, meta);

    // 4. grouped expert FFN (xcd-grouped queues)
    int pboff = combined ? 0 : NTOK;
    if (combined) {
        gemm_tile<0><<<dim3(8, QS0), 256, 0, stream>>>(
            hA, hB, w1t, meta, cnt, list, nullptr, b1,
            ubuf, nullptr, nullptr, nullptr, -1, 0, pboff);
        gemm_tile<1><<<dim3(8, QS1), 256, 0, stream>>>(
            ubuf, nullptr, w2t, meta, cnt, list, pbuf, b2,
            nullptr, moe, nullptr, nullptr, -1, 2, pboff);
    } else {
        for (int br = 0; br < NBR; ++br) {
            gemm_tile<0><<<dim3(8, QS0 / 2), 256, 0, stream>>>(
                hA, hB, w1t, meta, cnt, list, nullptr, b1,
                ubuf, nullptr, nullptr, nullptr, br, 0, pboff);
            gemm_tile<1><<<dim3(8, QS1 / 2), 256, 0, stream>>>(
                ubuf, nullptr, w2t, meta, cnt, list, pbuf, b2,
                nullptr, moe, nullptr, nullptr, br, br, pboff);
        }
    }

    // 5. stylization + output projection + residual
    eo_kernel<<<dim3(4, 16), 256, 0, stream>>>(emb, emb_w, emb_b, eo);
    stylize_kernel<<<NTOK / 4, 256, 0, stream>>>(moe, eo, sn_g, sn_b, hA, combined ? 1 : 0);
    gemm_tile<2><<<dim3(DD / 128, NTOK / 128), 256, 0, stream>>>(
        hA, nullptr, owt, meta, cnt, list, nullptr, out_b,
        nullptr, nullptr, x, (float*)d_out, 0, 0, 0);
}

// Round 4
// 491.641 us; speedup vs baseline: 1.0225x; 1.0225x over previous
//
#include <hip/hip_runtime.h>
#include <hip/hip_bf16.h>

typedef unsigned short u16;
typedef unsigned int u32;

typedef short bf16v8 __attribute__((ext_vector_type(8)));
typedef float f32v4 __attribute__((ext_vector_type(4)));

// ---------------- problem constants ----------------
constexpr int BB   = 64;
constexpr int TT   = 196;
constexpr int NTOK = BB * TT;   // 12544
constexpr int DD   = 512;
constexpr int FF   = 2048;
constexpr int EE   = 8;
constexpr int NBR  = 2;
constexpr int GE   = NBR * EE;  // 16 global experts
constexpr int QS0  = 416;       // fallback queue heights (128-tile path)
constexpr int QS1  = 104;
constexpr int MT256MAX = 114;   // max total 256-row tiles (<=112)

// meta: [0..15] u-row base per ge; [16..31] 128-tile counts; [32] n 256-mtiles;
// [48..63] 256-mtile starts; [64..64+nm) entries (ge<<16)|mt
__device__ __forceinline__ u16 f2bf(float f) {
    union { float f; u32 u; } v; v.f = f;
    u32 r = v.u + 0x7fffu + ((v.u >> 16) & 1u);
    return (u16)(r >> 16);
}

__device__ __forceinline__ float wave_sum(float v) {
    #pragma unroll
    for (int m = 32; m > 0; m >>= 1) v += __shfl_xor(v, m, 64);
    return v;
}

__device__ __forceinline__ float gelu_tanh(float v) {
    float z = 0.7978845608028654f * (v + 0.044715f * v * v * v);
    float az = fabsf(z);
    float e = __expf(-2.0f * az);
    float t = (1.0f - e) / (1.0f + e);
    t = (z < 0.0f) ? -t : t;
    return 0.5f * v * (1.0f + t);
}

__device__ __forceinline__ float silu(float v) {
    return v / (1.0f + __expf(-v));
}

__device__ __forceinline__ void gload16(const u16* g, u16* l) {
    typedef const __attribute__((address_space(1))) unsigned gv_t;
    typedef __attribute__((address_space(3))) unsigned lv_t;
    __builtin_amdgcn_global_load_lds((gv_t*)g, (lv_t*)l, 16, 0, 0);
}

__device__ __forceinline__ void bar() {
    asm volatile("" ::: "memory");
    __builtin_amdgcn_s_barrier();
    asm volatile("" ::: "memory");
}

#define ASM_VMCNT4 asm volatile("s_waitcnt vmcnt(4)" ::: "memory")
#define ASM_VMCNT0 asm volatile("s_waitcnt vmcnt(0)" ::: "memory")
#define ASM_LGKM0  asm volatile("s_waitcnt lgkmcnt(0)" ::: "memory")

// ---------------- merged transpose f32[R][C] -> bf16[C][R] -------------------
// flat grid: [0,16384) w1 slices; [16384,32768) w2 slices; [32768,33024) out_w
__global__ __launch_bounds__(256) void mtrans_kernel(
    const float* __restrict__ w1, u16* __restrict__ w1t,
    const float* __restrict__ w2, u16* __restrict__ w2t,
    const float* __restrict__ ow, u16* __restrict__ owt)
{
    __shared__ float tile[32][33];
    int id = blockIdx.x;
    const float* src; u16* dst; int R, C, rt, ct;
    if (id < 16384) {
        int e = id >> 10, rem = id & 1023;
        R = DD; C = FF; ct = rem & 63; rt = rem >> 6;
        src = w1 + (size_t)e * R * C; dst = w1t + (size_t)e * R * C;
    } else if (id < 32768) {
        int e = (id - 16384) >> 10, rem = (id - 16384) & 1023;
        R = FF; C = DD; ct = rem & 15; rt = rem >> 4;
        src = w2 + (size_t)e * R * C; dst = w2t + (size_t)e * R * C;
    } else {
        int rem = id - 32768;
        R = DD; C = DD; ct = rem & 15; rt = rem >> 4;
        src = ow; dst = owt;
    }
    int tx = threadIdx.x & 31, ty = threadIdx.x >> 5;
    int c0 = ct * 32, r0 = rt * 32;
    #pragma unroll
    for (int j = 0; j < 4; ++j)
        tile[ty + 8 * j][tx] = src[(size_t)(r0 + ty + 8 * j) * C + c0 + tx];
    __syncthreads();
    #pragma unroll
    for (int j = 0; j < 4; ++j)
        dst[(size_t)(c0 + ty + 8 * j) * R + r0 + tx] = f2bf(tile[tx][ty + 8 * j]);
}

// ---------------- LN + gate softmax/argmax (wave per token) ----------------
__global__ __launch_bounds__(256) void ln_gate_kernel(
    const float* __restrict__ x, const float* __restrict__ ln_g, const float* __restrict__ ln_b,
    const float* __restrict__ gate_w, const float* __restrict__ gate_b,
    u16* __restrict__ hA, u16* __restrict__ hB,
    int* __restrict__ idxb, float* __restrict__ pbuf)
{
    int wave = threadIdx.x >> 6, lane = threadIdx.x & 63;
    int tok = blockIdx.x * 4 + wave;
    const float* xr = x + (size_t)tok * DD + lane * 8;
    float4 v0 = *(const float4*)xr;
    float4 v1 = *(const float4*)(xr + 4);
    float xs[8] = {v0.x, v0.y, v0.z, v0.w, v1.x, v1.y, v1.z, v1.w};
    float s = 0.f, ss = 0.f;
    #pragma unroll
    for (int i = 0; i < 8; ++i) { s += xs[i]; ss += xs[i] * xs[i]; }
    s = wave_sum(s); ss = wave_sum(ss);
    float mu = s * (1.0f / DD);
    float var = ss * (1.0f / DD) - mu * mu;
    float rstd = rsqrtf(var + 1e-5f);

    #pragma unroll
    for (int br = 0; br < NBR; ++br) {
        u16* hb = br ? hB : hA;
        float part[8] = {0, 0, 0, 0, 0, 0, 0, 0};
        u16 hu[8];
        #pragma unroll
        for (int i = 0; i < 8; ++i) {
            int d = lane * 8 + i;
            float g = ln_g[br * DD + d], b = ln_b[br * DD + d];
            float h = (xs[i] - mu) * rstd * g + b;
            hu[i] = f2bf(h);
            const float* gw = gate_w + ((size_t)br * DD + d) * EE;
            float4 g0 = *(const float4*)gw;
            float4 g1 = *(const float4*)(gw + 4);
            part[0] += h * g0.x; part[1] += h * g0.y; part[2] += h * g0.z; part[3] += h * g0.w;
            part[4] += h * g1.x; part[5] += h * g1.y; part[6] += h * g1.z; part[7] += h * g1.w;
        }
        uint4 pk;
        pk.x = (u32)hu[0] | ((u32)hu[1] << 16);
        pk.y = (u32)hu[2] | ((u32)hu[3] << 16);
        pk.z = (u32)hu[4] | ((u32)hu[5] << 16);
        pk.w = (u32)hu[6] | ((u32)hu[7] << 16);
        *(uint4*)(hb + (size_t)tok * DD + lane * 8) = pk;

        float logit[8];
        #pragma unroll
        for (int e = 0; e < 8; ++e)
            logit[e] = wave_sum(part[e]) + gate_b[br * EE + e];
        float m = logit[0]; int bi = 0;
        #pragma unroll
        for (int e = 1; e < 8; ++e)
            if (logit[e] > m) { m = logit[e]; bi = e; }
        float sum = 0.f;
        #pragma unroll
        for (int e = 0; e < 8; ++e) sum += __expf(logit[e] - m);
        if (lane == 0) {
            idxb[br * NTOK + tok] = bi;
            pbuf[br * NTOK + tok] = 1.0f / sum;
        }
    }
}

// ---------------- routing ----------------
__global__ void route_kernel(const int* __restrict__ idxb, int* __restrict__ cnt,
                             int* __restrict__ list)
{
    int t = blockIdx.x * 256 + threadIdx.x;
    if (t >= NTOK) return;
    #pragma unroll
    for (int br = 0; br < NBR; ++br) {
        int e = idxb[br * NTOK + t];
        int slot = atomicAdd(&cnt[br * EE + e], 1);
        list[((size_t)(br * EE + e)) * NTOK + slot] = t;
    }
}

__global__ void tilestart_kernel(const int* __restrict__ cnt, int* __restrict__ meta)
{
    int lane = threadIdx.x;   // 64 threads
    int s_lo = 0, mstart = 0, myc = 0, nm = 0;
    #pragma unroll
    for (int k = 0; k < 16; ++k) {
        int ck = cnt[k];
        int mtk = (ck + 255) >> 8;
        if (k < (lane & 15)) { s_lo += ck; mstart += mtk; }
        if (k == (lane & 15)) myc = ck;
        nm += mtk;
    }
    if (lane < 16) {
        meta[lane] = s_lo;                   // u-row base (continuous)
        meta[16 + lane] = (myc + 127) >> 7;  // 128-tile count (fallback path)
        meta[48 + lane] = mstart;            // 256-tile start
    }
    if (lane == 16) meta[32] = nm;
    for (int j = lane; j < nm; j += 64) {
        int ge = -1, start = 0;
        #pragma unroll
        for (int k = 0; k < 16; ++k) {
            int mtk = (cnt[k] + 255) >> 8;
            if (ge < 0) {
                if (j < start + mtk) ge = k; else start += mtk;
            }
        }
        meta[64 + j] = (ge << 16) | (j - start);
    }
}

// ---------------- 256x256 grouped MFMA GEMM, BK=64, dbuf 2-phase, swizzled ---
// MODE 0: u[pos] = gelu(h[tok] @ W1[ge] + b1[ge])   (A gathered via list)
// MODE 1: moe{plane}[tok] = p * (u[pos] @ W2[ge] + b2[ge])  (A dense)
// grid: flat entries, j -> (mi = j/NT, nt = j%NT), entry = meta[64+mi]
template<int MODE>
__global__ __launch_bounds__(512, 2) void gemm256(
    const u16* __restrict__ A0, const u16* __restrict__ A1,
    const u16* __restrict__ Bt,
    const int* __restrict__ meta, const int* __restrict__ cnt,
    const int* __restrict__ list, const float* __restrict__ pbuf,
    const float* __restrict__ bias,
    u16* __restrict__ uout, float* __restrict__ moeout)
{
    constexpr int K = (MODE == 1) ? FF : DD;
    constexpr int N = (MODE == 0) ? FF : DD;
    constexpr int NT = N / 256;
    constexpr int NSTEP = K / 64;

    __shared__ __align__(16) u16 As[2][256 * 64];
    __shared__ __align__(16) u16 Bs[2][256 * 64];
    __shared__ int rowtok[256];

    int nm = meta[32];
    int j = blockIdx.x;
    if (j >= nm * NT) return;
    int mi = j / NT, nt = j % NT;
    int ev = meta[64 + mi];
    int ge = ev >> 16;
    int rb = (ev & 0xffff) << 8;
    int cnt_e = cnt[ge];
    int pb = meta[ge];

    int tid = threadIdx.x, wave = tid >> 6, lane = tid & 63;
    int wm = wave >> 2, wn = wave & 3;
    int fr = lane & 15, fq = lane >> 4;

    const u16* Bte = Bt + (size_t)ge * FF * DD;

    if constexpr (MODE == 1) {
        if (tid < 256) {
            int g = rb + tid;
            rowtok[tid] = (g < cnt_e) ? list[ge * NTOK + g] : -1;
        }
    }

    // ---- staging setup: waves 0-3 stage A, waves 4-7 stage B ----
    bool isA = wave < 4;
    int swv = isA ? wave : wave - 4;
    int srow = swv * 64 + (lane >> 3);             // + i*8
    int schunk = (lane & 7) ^ ((lane >> 3) & 7);   // inverse-swizzled source chunk
    const u16* sbase[8];
    #pragma unroll
    for (int i = 0; i < 8; ++i) {
        int r = srow + i * 8;
        if (isA) {
            if constexpr (MODE == 0) {
                int g = rb + r;
                int t = (g < cnt_e) ? list[ge * NTOK + g] : list[ge * NTOK];
                const u16* Ab = (ge >= 8) ? A1 : A0;
                sbase[i] = Ab + (size_t)t * K + schunk * 8;
            } else {
                sbase[i] = A0 + (size_t)(pb + rb + r) * K + schunk * 8;
            }
        } else {
            sbase[i] = Bte + (size_t)(nt * 256 + r) * K + schunk * 8;
        }
    }

    f32v4 acc[8][4];
    #pragma unroll
    for (int m = 0; m < 8; ++m)
        #pragma unroll
        for (int n = 0; n < 4; ++n)
            acc[m][n] = (f32v4){0.f, 0.f, 0.f, 0.f};

    // ---- prologue: stage K-tile 0 into buf 0 ----
    {
        u16* dstb = isA ? As[0] : Bs[0];
        #pragma unroll
        for (int i = 0; i < 8; ++i)
            gload16(sbase[i], dstb + (swv * 64 + i * 8) * 64);
    }
    ASM_VMCNT0;
    ASM_LGKM0;
    bar();

    // ---- 2-phase main loop: one vmcnt(0)+barrier per K-tile ----
    #pragma unroll 2
    for (int t = 0; t < NSTEP; ++t) {
        int cur = t & 1;
        if (t + 1 < NSTEP) {
            int koff = (t + 1) * 64;
            u16* dstb = isA ? As[cur ^ 1] : Bs[cur ^ 1];
            #pragma unroll
            for (int i = 0; i < 8; ++i)
                gload16(sbase[i] + koff, dstb + (swv * 64 + i * 8) * 64);
        }
        #pragma unroll
        for (int ks = 0; ks < 2; ++ks) {
            int ch = (ks * 4 + fq) ^ (fr & 7);
            bf16v8 af[8], bf[4];
            #pragma unroll
            for (int m = 0; m < 8; ++m)
                af[m] = *(const bf16v8*)&As[cur][(wm * 128 + m * 16 + fr) * 64 + ch * 8];
            #pragma unroll
            for (int n = 0; n < 4; ++n)
                bf[n] = *(const bf16v8*)&Bs[cur][(wn * 64 + n * 16 + fr) * 64 + ch * 8];
            #pragma unroll
            for (int m = 0; m < 8; ++m)
                #pragma unroll
                for (int n = 0; n < 4; ++n)
                    acc[m][n] = __builtin_amdgcn_mfma_f32_16x16x32_bf16(
                        af[m], bf[n], acc[m][n], 0, 0, 0);
        }
        ASM_VMCNT0;
        bar();
    }

    // ---- epilogue (C/D frag: col = lane&15, row = fq*4 + reg) ----
    #pragma unroll
    for (int m = 0; m < 8; ++m) {
        #pragma unroll
        for (int n = 0; n < 4; ++n) {
            int col = nt * 256 + wn * 64 + n * 16 + fr;
            float bn = bias[(size_t)ge * N + col];
            #pragma unroll
            for (int r = 0; r < 4; ++r) {
                int rr = wm * 128 + m * 16 + fq * 4 + r;
                float v = acc[m][n][r] + bn;
                if constexpr (MODE == 0) {
                    if (rb + rr < cnt_e)
                        uout[(size_t)(pb + rb + rr) * FF + col] = f2bf(gelu_tanh(v));
                } else {
                    int tok = rowtok[rr];
                    if (tok >= 0) {
                        float val = v * pbuf[(ge >> 3) * NTOK + tok];
                        moeout[((size_t)(ge >> 3) * NTOK + tok) * DD + col] = val;
                    }
                }
            }
        }
    }
}

// ---------------- 128x128 fallback / output-projection kernel ---------------
template<int MODE>
__global__ __launch_bounds__(256, 4) void gemm_tile(
    const u16* __restrict__ A0, const u16* __restrict__ A1,
    const u16* __restrict__ Bt,
    const int* __restrict__ meta, const int* __restrict__ cnt,
    const int* __restrict__ list, const float* __restrict__ pbuf,
    const float* __restrict__ bias,
    u16* __restrict__ uout, float* __restrict__ moeout,
    const float* __restrict__ xres, float* __restrict__ dout,
    int brsel, int addmode, int pboff)
{
    constexpr int K = (MODE == 1) ? FF : DD;
    constexpr int N = (MODE == 0) ? FF : DD;
    constexpr int NT = N / 128;
    constexpr int NSTEP = K / 32;

    __shared__ __align__(16) u16 As[2][128 * 32];
    __shared__ __align__(16) u16 Bs[2][128 * 32];
    __shared__ int rowtok[128];

    int tid = threadIdx.x, wave = tid >> 6, lane = tid & 63;
    int wm = wave >> 1, wn = wave & 1;
    int fr = lane & 15, fc = (lane >> 4) * 8;
    int r0 = wave * 16 + (lane >> 2);
    int hi = lane & 3;

    int eA = 0, eB = -1, nA = 0, qlen = 1;
    if constexpr (MODE != 2) {
        int q = blockIdx.x;
        if (brsel < 0)       { eA = q;     eB = q + 8; }
        else if (brsel == 0) { eA = q;     eB = -1; }
        else                 { eA = q + 8; eB = -1; }
        nA = meta[16 + eA] * NT;
        qlen = nA + ((eB >= 0) ? meta[16 + eB] * NT : 0);
    }

    for (int j = (MODE == 2) ? 0 : blockIdx.y;
         j < qlen;
         j += (MODE == 2) ? 1 : gridDim.y)
    {
        int ge = 0, rb, ntile, cnt_e = NTOK, pb = 0;
        if constexpr (MODE == 2) {
            rb = blockIdx.y * 128; ntile = blockIdx.x;
        } else {
            int loc;
            if (j < nA) { ge = eA; loc = j; }
            else        { ge = eB; loc = j - nA; }
            ntile = loc % NT;
            rb = (loc / NT) * 128;
            cnt_e = cnt[ge];
            pb = meta[ge] - ((ge >= 8) ? pboff : 0);
        }

        bar();

        const u16* Abase;
        if constexpr (MODE == 0) Abase = (ge >= 8) ? A1 : A0;
        else                     Abase = A0;
        const u16* Bte = Bt + ((MODE == 2) ? (size_t)0 : (size_t)ge * FF * DD);

        const u16 *aSrc0, *aSrc1, *bSrc0, *bSrc1;
        if constexpr (MODE == 0) {
            int lb = ge * NTOK;
            int g0 = rb + r0, g1 = g0 + 64;
            int t0 = (g0 < cnt_e) ? list[lb + g0] : list[lb];
            int t1 = (g1 < cnt_e) ? list[lb + g1] : list[lb];
            aSrc0 = Abase + (size_t)t0 * K + hi * 8;
            aSrc1 = Abase + (size_t)t1 * K + hi * 8;
        } else {
            size_t base = (MODE == 1) ? (size_t)(pb + rb) : (size_t)rb;
            aSrc0 = Abase + (base + r0) * (size_t)K + hi * 8;
            aSrc1 = Abase + (base + r0 + 64) * (size_t)K + hi * 8;
        }
        {
            int nrow = ntile * 128 + r0;
            bSrc0 = Bte + (size_t)nrow * K + hi * 8;
            bSrc1 = Bte + (size_t)(nrow + 64) * K + hi * 8;
        }

        if constexpr (MODE == 1) {
            if (tid < 128) {
                int g = rb + tid;
                rowtok[tid] = (g < cnt_e) ? list[ge * NTOK + g] : -1;
            }
            ASM_LGKM0;
        }

        f32v4 acc[4][4];
        #pragma unroll
        for (int mi = 0; mi < 4; ++mi)
            #pragma unroll
            for (int ni = 0; ni < 4; ++ni)
                acc[mi][ni] = (f32v4){0.f, 0.f, 0.f, 0.f};

        {
            gload16(aSrc0, &As[0][wave * 512]);
            gload16(aSrc1, &As[0][2048 + wave * 512]);
            gload16(bSrc0, &Bs[0][wave * 512]);
            gload16(bSrc1, &Bs[0][2048 + wave * 512]);
        }
        #pragma unroll 2
        for (int t = 0; t < NSTEP; ++t) {
            int cur = t & 1;
            if (t + 1 < NSTEP) {
                int k = (t + 1) * 32;
                gload16(aSrc0 + k, &As[cur ^ 1][wave * 512]);
                gload16(aSrc1 + k, &As[cur ^ 1][2048 + wave * 512]);
                gload16(bSrc0 + k, &Bs[cur ^ 1][wave * 512]);
                gload16(bSrc1 + k, &Bs[cur ^ 1][2048 + wave * 512]);
                ASM_VMCNT4;
            } else {
                ASM_VMCNT0;
            }
            bar();

            bf16v8 af[4], bfr[4];
            #pragma unroll
            for (int mi = 0; mi < 4; ++mi)
                af[mi] = *(const bf16v8*)&As[cur][(wm * 64 + mi * 16 + fr) * 32 + fc];
            #pragma unroll
            for (int ni = 0; ni < 4; ++ni)
                bfr[ni] = *(const bf16v8*)&Bs[cur][(wn * 64 + ni * 16 + fr) * 32 + fc];
            #pragma unroll
            for (int mi = 0; mi < 4; ++mi)
                #pragma unroll
                for (int ni = 0; ni < 4; ++ni)
                    acc[mi][ni] = __builtin_amdgcn_mfma_f32_16x16x32_bf16(
                        af[mi], bfr[ni], acc[mi][ni], 0, 0, 0);
            bar();
        }

        #pragma unroll
        for (int mi = 0; mi < 4; ++mi) {
            #pragma unroll
            for (int ni = 0; ni < 4; ++ni) {
                int col = ntile * 128 + wn * 64 + ni * 16 + fr;
                float bn = (MODE == 2) ? bias[col] : bias[(size_t)ge * N + col];
                #pragma unroll
                for (int r = 0; r < 4; ++r) {
                    int rr = wm * 64 + mi * 16 + (lane >> 4) * 4 + r;
                    float v = acc[mi][ni][r] + bn;
                    if constexpr (MODE == 0) {
                        if (rb + rr < cnt_e)
                            uout[(size_t)(pb + rb + rr) * FF + col] = f2bf(gelu_tanh(v));
                    } else if constexpr (MODE == 1) {
                        int tok = rowtok[rr];
                        if (tok >= 0) {
                            float val = v * pbuf[(ge >> 3) * NTOK + tok];
                            if (addmode == 2) {
                                moeout[((size_t)(ge >> 3) * NTOK + tok) * DD + col] = val;
                            } else {
                                float* o = &moeout[(size_t)tok * DD + col];
                                if (addmode) *o += val; else *o = val;
                            }
                        }
                    } else {
                        size_t o = (size_t)(rb + rr) * DD + col;
                        dout[o] = xres[o] + v;
                    }
                }
            }
        }
    }
}

// ---------------- eo = silu(emb) @ emb_w + emb_b  [64, 1024] ----------------
__global__ __launch_bounds__(256) void eo_kernel(
    const float* __restrict__ emb, const float* __restrict__ emb_w,
    const float* __restrict__ emb_b, float* __restrict__ eo)
{
    __shared__ float se[4][DD];
    int tid = threadIdx.x;
    int b0 = blockIdx.y * 4;
    int c0 = blockIdx.x * 256 + tid;
    for (int i = tid; i < 4 * DD; i += 256) {
        int b = i >> 9, d = i & (DD - 1);
        se[b][d] = silu(emb[(size_t)(b0 + b) * DD + d]);
    }
    __syncthreads();
    float acc[4] = {0, 0, 0, 0};
    for (int k = 0; k < DD; ++k) {
        float wv = emb_w[(size_t)k * 1024 + c0];
        #pragma unroll
        for (int b = 0; b < 4; ++b) acc[b] += se[b][k] * wv;
    }
    float bb = emb_b[c0];
    #pragma unroll
    for (int b = 0; b < 4; ++b)
        eo[(size_t)(b0 + b) * 1024 + c0] = acc[b] + bb;
}

// ---------------- stylize: LN(moe/NB)*(1+scale)+shift -> silu -> bf16 -------
__global__ __launch_bounds__(256) void stylize_kernel(
    const float* __restrict__ moe, const float* __restrict__ eo,
    const float* __restrict__ sn_g, const float* __restrict__ sn_b,
    u16* __restrict__ sbuf, int two)
{
    int wave = threadIdx.x >> 6, lane = threadIdx.x & 63;
    int tok = blockIdx.x * 4 + wave;
    int b = tok / TT;
    const float* mr = moe + (size_t)tok * DD + lane * 8;
    float4 v0 = *(const float4*)mr;
    float4 v1 = *(const float4*)(mr + 4);
    float os[8] = {v0.x, v0.y, v0.z, v0.w, v1.x, v1.y, v1.z, v1.w};
    if (two) {
        const float* mr2 = mr + (size_t)NTOK * DD;
        float4 w0 = *(const float4*)mr2;
        float4 w1 = *(const float4*)(mr2 + 4);
        os[0] += w0.x; os[1] += w0.y; os[2] += w0.z; os[3] += w0.w;
        os[4] += w1.x; os[5] += w1.y; os[6] += w1.z; os[7] += w1.w;
    }
    #pragma unroll
    for (int i = 0; i < 8; ++i) os[i] *= (1.0f / NBR);
    float s = 0.f, ss = 0.f;
    #pragma unroll
    for (int i = 0; i < 8; ++i) { s += os[i]; ss += os[i] * os[i]; }
    s = wave_sum(s); ss = wave_sum(ss);
    float mu = s * (1.0f / DD);
    float var = ss * (1.0f / DD) - mu * mu;
    float rstd = rsqrtf(var + 1e-5f);
    u16 hu[8];
    #pragma unroll
    for (int i = 0; i < 8; ++i) {
        int d = lane * 8 + i;
        float h = (os[i] - mu) * rstd * sn_g[d] + sn_b[d];
        float sc = eo[(size_t)b * 1024 + d];
        float sh = eo[(size_t)b * 1024 + DD + d];
        h = h * (1.0f + sc) + sh;
        hu[i] = f2bf(silu(h));
    }
    uint4 pk;
    pk.x = (u32)hu[0] | ((u32)hu[1] << 16);
    pk.y = (u32)hu[2] | ((u32)hu[3] << 16);
    pk.z = (u32)hu[4] | ((u32)hu[5] << 16);
    pk.w = (u32)hu[6] | ((u32)hu[7] << 16);
    *(uint4*)(sbuf + (size_t)tok * DD + lane * 8) = pk;
}

// ---------------- host ----------------
extern "C" void kernel_launch(void* const* d_in, const int* in_sizes, int n_in,
                              void* d_out, int out_size, void* d_ws, size_t ws_size,
                              hipStream_t stream)
{
    const float* x      = (const float*)d_in[0];
    const float* emb    = (const float*)d_in[1];
    const float* ln_g   = (const float*)d_in[2];
    const float* ln_b   = (const float*)d_in[3];
    const float* gate_w = (const float*)d_in[4];
    const float* gate_b = (const float*)d_in[5];
    const float* w1     = (const float*)d_in[6];
    const float* b1     = (const float*)d_in[7];
    const float* w2     = (const float*)d_in[8];
    const float* b2     = (const float*)d_in[9];
    const float* emb_w  = (const float*)d_in[10];
    const float* emb_b  = (const float*)d_in[11];
    const float* sn_g   = (const float*)d_in[12];
    const float* sn_b   = (const float*)d_in[13];
    const float* out_w  = (const float*)d_in[14];
    const float* out_b  = (const float*)d_in[15];
    (void)n_in; (void)in_sizes; (void)out_size;

    const size_t szW   = (size_t)GE * FF * DD * 2;
    const size_t szOwt = (size_t)DD * DD * 2;
    const size_t szH   = (size_t)NTOK * DD * 2;
    const size_t szEo  = (size_t)BB * 2 * DD * 4;
    const size_t szP   = (size_t)NBR * NTOK * 4;
    const size_t szCnt = 256, szMeta = 4096;
    const size_t szList = (size_t)GE * NTOK * 4;
    const size_t szU1  = ((size_t)NTOK + 512) * FF * 2;
    const size_t szU2  = ((size_t)2 * NTOK + 512) * FF * 2;
    const size_t szM1  = (size_t)NTOK * DD * 4;
    const size_t szM2  = (size_t)2 * NTOK * DD * 4;

    auto align256 = [](size_t v) { return (v + 255) & ~(size_t)255; };
    size_t fixed = align256(szW) + align256(szW) + align256(szOwt) + align256(szH) * 2 +
                   align256(szEo) + align256(szP) * 2 + align256(szCnt) + align256(szMeta) +
                   align256(szList);
    bool combined = ws_size >= fixed + align256(szU2) + align256(szM2) + (1u << 20);

    char* w = (char*)d_ws;
    size_t off = 0;
    auto take = [&](size_t bytes) -> void* {
        void* p = w + off;
        off = align256(off + bytes);
        return p;
    };
    u16*   w1t  = (u16*)take(szW);
    u16*   w2t  = (u16*)take(szW);
    u16*   owt  = (u16*)take(szOwt);
    u16*   hA   = (u16*)take(szH);       // reused as sbuf
    u16*   hB   = (u16*)take(szH);
    float* eo   = (float*)take(szEo);
    float* pbuf = (float*)take(szP);
    int*   idxb = (int*)take(szP);
    int*   cnt  = (int*)take(szCnt);
    int*   meta = (int*)take(szMeta);
    int*   list = (int*)take(szList);
    u16*   ubuf = (u16*)take(combined ? szU2 : szU1);
    float* moe  = (float*)take(combined ? szM2 : szM1);

    // 1. weight transposes -> bf16 [N][K] (one merged dispatch)
    mtrans_kernel<<<33024, 256, 0, stream>>>(w1, w1t, w2, w2t, out_w, owt);

    // 2. LN + gate
    ln_gate_kernel<<<NTOK / 4, 256, 0, stream>>>(x, ln_g, ln_b, gate_w, gate_b, hA, hB, idxb, pbuf);

    // 3. routing
    hipMemsetAsync(cnt, 0, 64, stream);
    route_kernel<<<(NTOK + 255) / 256, 256, 0, stream>>>(idxb, cnt, list);
    tilestart_kernel<<<1, 64, 0, stream>>>(cnt, meta);

    // 4. grouped expert FFN
    if (combined) {
        gemm256<0><<<MT256MAX * (FF / 256), 512, 0, stream>>>(
            hA, hB, w1t, meta, cnt, list, nullptr, b1, ubuf, nullptr);
        gemm256<1><<<MT256MAX * (DD / 256), 512, 0, stream>>>(
            ubuf, nullptr, w2t, meta, cnt, list, pbuf, b2, nullptr, moe);
    } else {
        for (int br = 0; br < NBR; ++br) {
            gemm_tile<0><<<dim3(8, QS0 / 2), 256, 0, stream>>>(
                hA, hB, w1t, meta, cnt, list, nullptr, b1,
                ubuf, nullptr, nullptr, nullptr, br, 0, NTOK);
            gemm_tile<1><<<dim3(8, QS1 / 2), 256, 0, stream>>>(
                ubuf, nullptr, w2t, meta, cnt, list, pbuf, b2,
                nullptr, moe, nullptr, nullptr, br, br, NTOK);
        }
    }

    // 5. stylization + output projection + residual
    eo_kernel<<<dim3(4, 16), 256, 0, stream>>>(emb, emb_w, emb_b, eo);
    stylize_kernel<<<NTOK / 4, 256, 0, stream>>>(moe, eo, sn_g, sn_b, hA, combined ? 1 : 0);
    gemm_tile<2><<<dim3(DD / 128, NTOK / 128), 256, 0, stream>>>(
        hA, nullptr, owt, meta, cnt, list, nullptr, out_b,
        nullptr, nullptr, x, (float*)d_out, 0, 0, 0);
}